// Round 3
// baseline (135.828 us; speedup 1.0000x reference)
//
#include <hip/hip_runtime.h>

// EnsembleGRU fused kernel, R1 (resubmit — R2 bench was an infra failure).
// Shapes: inputs (W=64, E=16, B*I=2560, F=8) f32; out (W, E, B*I, 1) f32.
// Math fold: gi = W_ih·(W_lin·x + b_lin) + b_ih  ==  M·x + c, M = W_ih·W_lin (3x8).
// Gates pre-scaled so each is rcp(1+exp2(fma)) with no extra ops on the h-chain:
//   r = sigmoid(a)  = rcp(1 + exp2(-L2E*a))     -> fold -L2E into M0,c0,w0
//   z likewise with M1,c1,w1
//   n = tanh(t)     = 1 - 2*rcp(1 + exp2(2*L2E*t)) -> fold 2*L2E into M2,c2,w2,bh2
// Key points: named double buffers bA/bB (no runtime-indexed register array ->
// no scratch), hoisted h-independent gi FMAs per chunk, exp2/rcp intrinsics on
// the serial chain.

namespace {
constexpr int W_T = 64;
constexpr int E_N = 16;
constexpr int B_N = 256;
constexpr int I_N = 10;
constexpr int F_N = 8;
constexpr int PROJ = 16;
constexpr int BI = B_N * I_N;           // 2560
constexpr int WSTRIDE = E_N * BI * F_N; // 327680 floats per timestep
constexpr int OSTRIDE = E_N * BI;       // 40960 floats per timestep
constexpr int NCHAIN = E_N * BI;        // 40960 chains
constexpr int BLOCKS_PER_E = BI / 64;   // 40
constexpr float L2E = 1.44269504088896340736f;
constexpr int CH = 8;                   // timesteps per chunk
constexpr int NC = W_T / CH;            // 8 chunks
} // namespace

__global__ __launch_bounds__(64, 1) void EnsembleGRUModule_63213328662935_kernel(
    const float* __restrict__ x,    // (W,E,BI,F)
    const float* __restrict__ h0p,  // (1,E,BI,1)
    const float* __restrict__ wl,   // (E,16,8)
    const float* __restrict__ bl,   // (E,16)
    const float* __restrict__ wih,  // (E,3,16)
    const float* __restrict__ whh,  // (E,3,1)
    const float* __restrict__ bih,  // (E,3)
    const float* __restrict__ bhh,  // (E,3)
    float* __restrict__ out)        // (W,E,BI)
{
    const int e = blockIdx.x / BLOCKS_PER_E;            // block-uniform -> scalar loads
    const int bi = (blockIdx.x % BLOCKS_PER_E) * 64 + threadIdx.x;
    const int chain = e * BI + bi;

    // ---- fold the two linear layers: M[3][8], c[3] (one-time, ~400 FMA) ----
    const float* wl_e = wl + e * (PROJ * F_N);
    const float* wih_e = wih + e * (3 * PROJ);
    float M[3][F_N];
    float c[3];
    #pragma unroll
    for (int g = 0; g < 3; ++g) {
        float cg = bih[e * 3 + g];
        float m[F_N];
        #pragma unroll
        for (int f = 0; f < F_N; ++f) m[f] = 0.f;
        #pragma unroll
        for (int o = 0; o < PROJ; ++o) {
            const float wgo = wih_e[g * PROJ + o];
            cg = __builtin_fmaf(wgo, bl[e * PROJ + o], cg);
            #pragma unroll
            for (int f = 0; f < F_N; ++f)
                m[f] = __builtin_fmaf(wgo, wl_e[o * F_N + f], m[f]);
        }
        #pragma unroll
        for (int f = 0; f < F_N; ++f) M[g][f] = m[f];
        c[g] = cg;
    }
    // ---- pre-scale for exp2-form gates ----
    float M0[F_N], M1[F_N], M2[F_N];
    #pragma unroll
    for (int f = 0; f < F_N; ++f) {
        M0[f] = -L2E * M[0][f];
        M1[f] = -L2E * M[1][f];
        M2[f] = 2.f * L2E * M[2][f];
    }
    const float c0s = -L2E * (c[0] + bhh[e * 3 + 0]);
    const float c1s = -L2E * (c[1] + bhh[e * 3 + 1]);
    const float c2s = 2.f * L2E * c[2];
    const float W0s = -L2E * whh[e * 3 + 0];
    const float W1s = -L2E * whh[e * 3 + 1];
    const float W2s = 2.f * L2E * whh[e * 3 + 2];
    const float bh2s = 2.f * L2E * bhh[e * 3 + 2];

    const float* xp = x + (size_t)chain * F_N;
    float* op = out + chain;
    float h = h0p[chain];

    // ---- named double buffers: registers guaranteed (constant indices only) ----
    float4 bA[CH][2], bB[CH][2];

    auto LOADC = [&](float4 (&b)[CH][2], int cidx) {
        #pragma unroll
        for (int j = 0; j < CH; ++j) {
            const float* p = xp + (size_t)(cidx * CH + j) * WSTRIDE;
            b[j][0] = *(const float4*)p;
            b[j][1] = *(const float4*)(p + 4);
        }
    };
    auto COMPUTE = [&](const float4 (&b)[CH][2], int cidx) {
        // hoisted h-independent gate pre-activations for the whole chunk
        float g0[CH], g1[CH], g2[CH];
        #pragma unroll
        for (int j = 0; j < CH; ++j) {
            const float xv[8] = {b[j][0].x, b[j][0].y, b[j][0].z, b[j][0].w,
                                 b[j][1].x, b[j][1].y, b[j][1].z, b[j][1].w};
            float a0 = c0s, a1 = c1s, a2 = c2s;
            #pragma unroll
            for (int f = 0; f < 8; ++f) {
                a0 = __builtin_fmaf(M0[f], xv[f], a0);
                a1 = __builtin_fmaf(M1[f], xv[f], a1);
                a2 = __builtin_fmaf(M2[f], xv[f], a2);
            }
            g0[j] = a0; g1[j] = a1; g2[j] = a2;
        }
        // serial h-chain: per step ~ fma,exp2,add,rcp (r,z in parallel) + fma,exp2,add,rcp,fma (n) + sub,fma
        #pragma unroll
        for (int j = 0; j < CH; ++j) {
            const float r  = __builtin_amdgcn_rcpf(
                1.f + __builtin_amdgcn_exp2f(__builtin_fmaf(W0s, h, g0[j])));
            const float z  = __builtin_amdgcn_rcpf(
                1.f + __builtin_amdgcn_exp2f(__builtin_fmaf(W1s, h, g1[j])));
            const float gh2 = __builtin_fmaf(W2s, h, bh2s);
            const float t   = __builtin_fmaf(r, gh2, g2[j]);
            const float n   = __builtin_fmaf(
                -2.f, __builtin_amdgcn_rcpf(1.f + __builtin_amdgcn_exp2f(t)), 1.f);
            h = __builtin_fmaf(z, h - n, n);
            op[(size_t)(cidx * CH + j) * OSTRIDE] = h;
        }
    };

    LOADC(bA, 0);
    LOADC(bB, 1);
    #pragma unroll
    for (int cidx = 0; cidx < NC; cidx += 2) {
        COMPUTE(bA, cidx);
        if (cidx + 2 < NC) LOADC(bA, cidx + 2);   // in flight under COMPUTE(bB)
        COMPUTE(bB, cidx + 1);
        if (cidx + 3 < NC) LOADC(bB, cidx + 3);   // in flight under next COMPUTE(bA)
    }
}

extern "C" void kernel_launch(void* const* d_in, const int* in_sizes, int n_in,
                              void* d_out, int out_size, void* d_ws, size_t ws_size,
                              hipStream_t stream) {
    const float* x   = (const float*)d_in[0];
    const float* st  = (const float*)d_in[1];
    const float* wl  = (const float*)d_in[2];
    const float* bl  = (const float*)d_in[3];
    const float* wih = (const float*)d_in[4];
    const float* whh = (const float*)d_in[5];
    const float* bih = (const float*)d_in[6];
    const float* bhh = (const float*)d_in[7];
    float* out = (float*)d_out;

    dim3 grid(NCHAIN / 64);
    dim3 block(64);
    hipLaunchKernelGGL(EnsembleGRUModule_63213328662935_kernel, grid, block, 0, stream,
                       x, st, wl, bl, wih, whh, bih, bhh, out);
}